// Round 1
// baseline (4972.756 us; speedup 1.0000x reference)
//
#include <hip/hip_runtime.h>
#include <hip/hip_bf16.h>
#include <math.h>

typedef unsigned short u16;
typedef unsigned int u32;
typedef __attribute__((ext_vector_type(8))) short short8;
typedef __attribute__((ext_vector_type(4))) float float4v;

#define DEV __device__ __forceinline__

DEV u16 f2bf(float x) {
    __hip_bfloat16 h = __float2bfloat16(x);
    return *reinterpret_cast<u16*>(&h);
}

// ---------------------------------------------------------------------------
// Embedding: h[t,:] = bpe[x[t],:] + pe[t%128,:]  (writes f32 + bf16 copies)
// ---------------------------------------------------------------------------
__global__ __launch_bounds__(256) void embed_k(const int* __restrict__ x,
                                               const float* __restrict__ bpe,
                                               const float* __restrict__ pe,
                                               float* __restrict__ hf, u16* __restrict__ hb) {
    long trow = blockIdx.x;
    int s = (int)(trow & 127);
    long tok = x[trow];
    int t = threadIdx.x;
#pragma unroll
    for (int kk = 0; kk < 3; kk++) {
        int j = t + kk * 256;
        float v = bpe[tok * 768 + j] + pe[(long)s * 768 + j];
        hf[trow * 768 + j] = v;
        hb[trow * 768 + j] = f2bf(v);
    }
}

// ---------------------------------------------------------------------------
// LayerNorm over rows of 768: out f32 + bf16
// ---------------------------------------------------------------------------
__global__ __launch_bounds__(256) void layernorm_k(const float* __restrict__ in,
                                                   const float* __restrict__ w,
                                                   const float* __restrict__ bb,
                                                   float* __restrict__ hf, u16* __restrict__ hb) {
    long trow = blockIdx.x;
    const float* xp = in + trow * 768;
    int t = threadIdx.x;
    float v[3];
    float s = 0.f, sq = 0.f;
#pragma unroll
    for (int kk = 0; kk < 3; kk++) {
        v[kk] = xp[t + kk * 256];
        s += v[kk];
        sq += v[kk] * v[kk];
    }
#pragma unroll
    for (int off = 32; off; off >>= 1) {
        s += __shfl_xor(s, off);
        sq += __shfl_xor(sq, off);
    }
    __shared__ float rs[4], rq[4];
    int wave = t >> 6, lane = t & 63;
    if (lane == 0) { rs[wave] = s; rq[wave] = sq; }
    __syncthreads();
    s = rs[0] + rs[1] + rs[2] + rs[3];
    sq = rq[0] + rq[1] + rq[2] + rq[3];
    float mu = s * (1.f / 768.f);
    float var = sq * (1.f / 768.f) - mu * mu;
    float rstd = rsqrtf(var + 1e-5f);
#pragma unroll
    for (int kk = 0; kk < 3; kk++) {
        int j = t + kk * 256;
        float y = (v[kk] - mu) * rstd * w[j] + bb[j];
        hf[trow * 768 + j] = y;
        hb[trow * 768 + j] = f2bf(y);
    }
}

// ---------------------------------------------------------------------------
// Transpose + f32->bf16 convert: dst[c][r] = src[r][c], zero-pad rows c in [C,Cpad)
// grid.z: batched sub-matrices (per-head for QKV repack)
// ---------------------------------------------------------------------------
__global__ __launch_bounds__(256) void transpose_cvt(const float* __restrict__ src,
                                                     u16* __restrict__ dst,
                                                     int R, int C, int src_ld, int dst_ld,
                                                     int Cpad, size_t src_zstride, int dst_zrows) {
    __shared__ float tile[32][33];
    src += (size_t)blockIdx.z * src_zstride;
    dst += (size_t)blockIdx.z * (size_t)dst_zrows * dst_ld;
    int tx = threadIdx.x & 31, ty = threadIdx.x >> 5;  // 32 x 8
    int r0 = blockIdx.y * 32, c0 = blockIdx.x * 32;
#pragma unroll
    for (int i = 0; i < 4; i++) {
        int r = r0 + ty + i * 8, c = c0 + tx;
        tile[ty + i * 8][tx] = (r < R && c < C) ? src[(size_t)r * src_ld + c] : 0.f;
    }
    __syncthreads();
#pragma unroll
    for (int i = 0; i < 4; i++) {
        int c = c0 + ty + i * 8, r = r0 + tx;
        if (c < Cpad && r < R) dst[(size_t)c * dst_ld + r] = f2bf(tile[tx][ty + i * 8]);
    }
}

// ---------------------------------------------------------------------------
// Pack QKV bias [768|768|768] -> qkvb[2304]
// ---------------------------------------------------------------------------
__global__ void pack_qkv_bias(const float* __restrict__ bq, const float* __restrict__ bk,
                              const float* __restrict__ bv, float* __restrict__ qkvb) {
    int j = blockIdx.x * 256 + threadIdx.x;
    if (j < 2304) qkvb[j] = (j < 768) ? bq[j] : (j < 1536 ? bk[j - 768] : bv[j - 1536]);
}

// ---------------------------------------------------------------------------
// GEMM: C[M,N] = A[M,K](bf16,row-major) @ Bt[N,K](bf16,row-major)^T + bias
// 128x128 tile, BK=32, 256 threads (4 waves, each 64x64 via 4x4 mfma 16x16x32)
// EPI: 0 = store f32 (acc+bias)
//      1 = store f32 (acc+bias+res_in)            [attn out proj + residual]
//      2 = store bf16 (acc+bias)                  [FFN1 -> t1]
//      3 = store f32 (res_in + gelu(acc+bias))    [FFN2 + gelu + residual]
// ---------------------------------------------------------------------------
template <int EPI>
__global__ __launch_bounds__(256) void gemm_bt(const u16* __restrict__ A,
                                               const u16* __restrict__ Bt,
                                               const float* __restrict__ bias,
                                               const float* __restrict__ res_in,
                                               float* __restrict__ outf, u16* __restrict__ outb,
                                               int M, int N, int K) {
    __shared__ __align__(16) u16 As[128 * 32];
    __shared__ __align__(16) u16 Bs[128 * 32];
    const int t = threadIdx.x;
    const int lane = t & 63, wave = t >> 6;
    const int ln15 = lane & 15, quad = lane >> 4;
    const int wm = (wave >> 1) * 64, wn = (wave & 1) * 64;
    const long m0 = (long)blockIdx.y * 128, n0 = (long)blockIdx.x * 128;

    float4v acc[4][4];
#pragma unroll
    for (int i = 0; i < 4; i++)
#pragma unroll
        for (int j = 0; j < 4; j++) acc[i][j] = float4v{0.f, 0.f, 0.f, 0.f};

    for (int kb = 0; kb < K; kb += 32) {
#pragma unroll
        for (int i = 0; i < 2; i++) {
            int li = i * 256 + t;
            const u16* gp = A + (m0 + (li >> 2)) * (long)K + kb + (li & 3) * 8;
            __builtin_amdgcn_global_load_lds(
                (const __attribute__((address_space(1))) u32*)gp,
                (__attribute__((address_space(3))) u32*)(As + li * 8), 16, 0, 0);
        }
#pragma unroll
        for (int i = 0; i < 2; i++) {
            int li = i * 256 + t;
            const u16* gp = Bt + (n0 + (li >> 2)) * (long)K + kb + (li & 3) * 8;
            __builtin_amdgcn_global_load_lds(
                (const __attribute__((address_space(1))) u32*)gp,
                (__attribute__((address_space(3))) u32*)(Bs + li * 8), 16, 0, 0);
        }
        __syncthreads();
        short8 af[4], bfr[4];
#pragma unroll
        for (int ti = 0; ti < 4; ti++)
            af[ti] = *(const short8*)(As + (wm + ti * 16 + ln15) * 32 + quad * 8);
#pragma unroll
        for (int tj = 0; tj < 4; tj++)
            bfr[tj] = *(const short8*)(Bs + (wn + tj * 16 + ln15) * 32 + quad * 8);
#pragma unroll
        for (int ti = 0; ti < 4; ti++)
#pragma unroll
            for (int tj = 0; tj < 4; tj++)
                acc[ti][tj] = __builtin_amdgcn_mfma_f32_16x16x32_bf16(af[ti], bfr[tj],
                                                                     acc[ti][tj], 0, 0, 0);
        __syncthreads();
    }

#pragma unroll
    for (int ti = 0; ti < 4; ti++) {
#pragma unroll
        for (int r = 0; r < 4; r++) {
            long gm = m0 + wm + ti * 16 + quad * 4 + r;
#pragma unroll
            for (int tj = 0; tj < 4; tj++) {
                long gn = n0 + wn + tj * 16 + ln15;
                if (gn < N) {
                    float v = acc[ti][tj][r] + bias[gn];
                    if constexpr (EPI == 0) {
                        outf[gm * N + gn] = v;
                    } else if constexpr (EPI == 1) {
                        outf[gm * N + gn] = v + res_in[gm * N + gn];
                    } else if constexpr (EPI == 2) {
                        outb[gm * N + gn] = f2bf(v);
                    } else {
                        float g = 0.5f * v * (1.f + erff(v * 0.70710678118654752f));
                        outf[gm * N + gn] = res_in[gm * N + gn] + g;
                    }
                }
            }
        }
    }
}

// ---------------------------------------------------------------------------
// Attention: one block per (b,h). S=128, HD=64. f32 math.
// qkv layout: [t=b*128+s][2304] with cols 0..767=Q, 768..1535=K, 1536..2303=V
// writes o (concat heads) as bf16 [t][768]
// ---------------------------------------------------------------------------
__global__ __launch_bounds__(256) void attn_k(const float* __restrict__ qkv,
                                              const int* __restrict__ ignore,
                                              u16* __restrict__ obf) {
    const int bh = blockIdx.x;
    const int b = bh / 12, h = bh % 12;
    __shared__ float ks[128][65];
    __shared__ float vs[128][64];
    __shared__ float qrow[4][64];
    __shared__ float ps[4][128];
    __shared__ int ig[128];
    const int t = threadIdx.x;
    for (int i = t; i < 128 * 64; i += 256) {
        int s = i >> 6, e = i & 63;
        size_t base = ((size_t)(b * 128 + s)) * 2304 + h * 64 + e;
        ks[s][e] = qkv[base + 768];
        vs[s][e] = qkv[base + 1536];
    }
    if (t < 128) ig[t] = ignore[b * 128 + t];
    __syncthreads();
    const int wave = t >> 6, lane = t & 63;
    for (int r = wave; r < 128; r += 4) {
        qrow[wave][lane] = qkv[((size_t)(b * 128 + r)) * 2304 + h * 64 + lane];
        float s1 = 0.f, s2 = 0.f;
#pragma unroll 8
        for (int e = 0; e < 64; e++) {
            float qe = qrow[wave][e];
            s1 = fmaf(qe, ks[lane][e], s1);
            s2 = fmaf(qe, ks[lane + 64][e], s2);
        }
        s1 *= 0.125f;  // 1/sqrt(64)
        s2 *= 0.125f;
        int k1 = lane, k2 = lane + 64;
        bool ok1 = (k1 <= r) && (ig[k1] == 0 || k1 == r);
        bool ok2 = (k2 <= r) && (ig[k2] == 0 || k2 == r);
        if (!ok1) s1 = -3.0e38f;
        if (!ok2) s2 = -3.0e38f;
        float mx = fmaxf(s1, s2);
#pragma unroll
        for (int off = 32; off; off >>= 1) mx = fmaxf(mx, __shfl_xor(mx, off));
        float e1 = expf(s1 - mx), e2 = expf(s2 - mx);
        float sm = e1 + e2;
#pragma unroll
        for (int off = 32; off; off >>= 1) sm += __shfl_xor(sm, off);
        float inv = 1.f / sm;
        ps[wave][k1] = e1 * inv;
        ps[wave][k2] = e2 * inv;
        float o = 0.f;
#pragma unroll 8
        for (int kp = 0; kp < 128; kp++) o = fmaf(ps[wave][kp], vs[kp][lane], o);
        obf[((size_t)(b * 128 + r)) * 768 + h * 64 + lane] = f2bf(o);
    }
}

// ---------------------------------------------------------------------------
extern "C" void kernel_launch(void* const* d_in, const int* in_sizes, int n_in,
                              void* d_out, int out_size, void* d_ws, size_t ws_size,
                              hipStream_t stream) {
    const int* x     = (const int*)d_in[0];
    const int* ign   = (const int*)d_in[1];
    const float* bpe = (const float*)d_in[2];
    const float* pe  = (const float*)d_in[3];
    const float* Wq  = (const float*)d_in[4];
    const float* bq  = (const float*)d_in[5];
    const float* Wk  = (const float*)d_in[6];
    const float* bk  = (const float*)d_in[7];
    const float* Wv  = (const float*)d_in[8];
    const float* bv  = (const float*)d_in[9];
    const float* Wo  = (const float*)d_in[10];
    const float* bo  = (const float*)d_in[11];
    const float* W1  = (const float*)d_in[12];
    const float* b1  = (const float*)d_in[13];
    const float* W2  = (const float*)d_in[14];
    const float* b2  = (const float*)d_in[15];
    const float* ln1w = (const float*)d_in[16];
    const float* ln1b = (const float*)d_in[17];
    const float* ln2w = (const float*)d_in[18];
    const float* ln2b = (const float*)d_in[19];
    const float* Wout = (const float*)d_in[20];
    const float* bout = (const float*)d_in[21];
    float* out = (float*)d_out;

    char* p = (char*)d_ws;
    auto alloc = [&](size_t bytes) {
        char* r = p;
        p += (bytes + 255) & ~(size_t)255;
        return r;
    };
    float* hf   = (float*)alloc((size_t)2048 * 768 * 4);
    u16* hb     = (u16*)alloc((size_t)2048 * 768 * 2);
    float* res  = (float*)alloc((size_t)2048 * 768 * 4);
    float* qkv  = (float*)alloc((size_t)2048 * 2304 * 4);
    u16* obf    = (u16*)alloc((size_t)2048 * 768 * 2);
    u16* t1b    = (u16*)alloc((size_t)2048 * 3072 * 2);
    u16* Wqkv_t = (u16*)alloc((size_t)2304 * 768 * 2);
    u16* Wo_t   = (u16*)alloc((size_t)768 * 768 * 2);
    u16* W1_t   = (u16*)alloc((size_t)3072 * 768 * 2);
    u16* W2_t   = (u16*)alloc((size_t)768 * 3072 * 2);
    u16* Wout_t = (u16*)alloc((size_t)40064 * 768 * 2);
    float* qkvb = (float*)alloc(2304 * 4);

    embed_k<<<2048, 256, 0, stream>>>(x, bpe, pe, hf, hb);

    for (int l = 0; l < 12; l++) {
        // repack Wq/Wk/Wv -> Wqkv_t [2304 x 768] bf16 (row j=h*64+e, col d)
        transpose_cvt<<<dim3(2, 24, 12), 256, 0, stream>>>(
            Wq + (size_t)l * 12 * 768 * 64, Wqkv_t, 768, 64, 64, 768, 64,
            (size_t)768 * 64, 64);
        transpose_cvt<<<dim3(2, 24, 12), 256, 0, stream>>>(
            Wk + (size_t)l * 12 * 768 * 64, Wqkv_t + (size_t)768 * 768, 768, 64, 64, 768, 64,
            (size_t)768 * 64, 64);
        transpose_cvt<<<dim3(2, 24, 12), 256, 0, stream>>>(
            Wv + (size_t)l * 12 * 768 * 64, Wqkv_t + (size_t)1536 * 768, 768, 64, 64, 768, 64,
            (size_t)768 * 64, 64);
        pack_qkv_bias<<<9, 256, 0, stream>>>(bq + l * 768, bk + l * 768, bv + l * 768, qkvb);
        // QKV GEMM -> qkv f32 [2048 x 2304]
        gemm_bt<0><<<dim3(18, 16), 256, 0, stream>>>(hb, Wqkv_t, qkvb, nullptr, qkv, nullptr,
                                                     2048, 2304, 768);
        // attention -> obf bf16 [2048 x 768]
        attn_k<<<192, 256, 0, stream>>>(qkv, ign, obf);
        // out proj + residual -> res f32
        transpose_cvt<<<dim3(24, 24, 1), 256, 0, stream>>>(Wo + (size_t)l * 768 * 768, Wo_t,
                                                           768, 768, 768, 768, 768, 0, 0);
        gemm_bt<1><<<dim3(6, 16), 256, 0, stream>>>(obf, Wo_t, bo + l * 768, hf, res, nullptr,
                                                    2048, 768, 768);
        layernorm_k<<<2048, 256, 0, stream>>>(res, ln1w + l * 768, ln1b + l * 768, hf, hb);
        // FFN1 -> t1 bf16 [2048 x 3072]
        transpose_cvt<<<dim3(96, 24, 1), 256, 0, stream>>>(W1 + (size_t)l * 768 * 3072, W1_t,
                                                           768, 3072, 3072, 768, 3072, 0, 0);
        gemm_bt<2><<<dim3(24, 16), 256, 0, stream>>>(hb, W1_t, b1 + l * 3072, nullptr, nullptr,
                                                     t1b, 2048, 3072, 768);
        // FFN2 + gelu + residual -> res f32
        transpose_cvt<<<dim3(24, 96, 1), 256, 0, stream>>>(W2 + (size_t)l * 3072 * 768, W2_t,
                                                           3072, 768, 768, 3072, 768, 0, 0);
        gemm_bt<3><<<dim3(6, 16), 256, 0, stream>>>(t1b, W2_t, b2 + l * 768, hf, res, nullptr,
                                                    2048, 768, 3072);
        layernorm_k<<<2048, 256, 0, stream>>>(res, ln2w + l * 768, ln2b + l * 768, hf, hb);
    }

    // final vocab projection: out[2048 x 40000] f32
    transpose_cvt<<<dim3(1252, 24, 1), 256, 0, stream>>>(Wout, Wout_t, 768, 40000, 40000, 768,
                                                         40064, 0, 0);
    gemm_bt<0><<<dim3(313, 16), 256, 0, stream>>>(hb, Wout_t, bout, nullptr, out, nullptr,
                                                  2048, 40000, 768);
}